// Round 8
// baseline (311.303 us; speedup 1.0000x reference)
//
#include <hip/hip_runtime.h>
#include <cstdint>
#include <cstddef>

// Problem constants
constexpr int B = 32, C = 256, H = 32, W = 32;
constexpr int NPTS = B * H * W;          // 32768 points
constexpr int DIM  = 256;                // embedding dim
constexpr int K    = 1024;               // codebook size
constexpr int QELEMS = B * C * H * W;    // 8388608 quantized elements
constexpr int CHW = C * H * W;           // 262144

typedef __attribute__((ext_vector_type(8))) short s8v;    // 8 bf16 (4 VGPRs)
typedef __attribute__((ext_vector_type(4))) float f32x4;  // MFMA acc

// Async global->LDS, 16B per lane. LDS dest is wave-uniform base + lane*16.
#define GLD_LDS16(g, l)                                                        \
  __builtin_amdgcn_global_load_lds(                                            \
      (const __attribute__((address_space(1))) unsigned int*)(g),              \
      (__attribute__((address_space(3))) unsigned int*)(l), 16, 0, 0)

__device__ __forceinline__ unsigned short f2bf(float f) {  // RNE fp32->bf16
  unsigned u = __float_as_uint(f);
  return (unsigned short)((u + 0x7FFFu + ((u >> 16) & 1u)) >> 16);
}

// ---------------- eprep: ehi[k][c] bf16 + ||e_k||^2 ----------
__global__ __launch_bounds__(256) void eprep_kernel(const float* __restrict__ emb,
                                                    unsigned short* __restrict__ ehi,
                                                    float* __restrict__ esq) {
  __shared__ float sums[4][64];
  const int t = threadIdx.x;
  const int k = blockIdx.x * 64 + (t & 63);   // grid = K/64
  const int seg = t >> 6;                     // 4 segs x 64 c
  const float* er = emb + (size_t)k * DIM + seg * 64;
  float v[64];
  float4* v4 = (float4*)v;
#pragma unroll
  for (int i = 0; i < 16; ++i) v4[i] = *(const float4*)(er + i * 4);
  float s = 0.f;
#pragma unroll
  for (int i = 0; i < 64; ++i) s = fmaf(v[i], v[i], s);
  unsigned short* eo = ehi + (size_t)k * DIM + seg * 64;
#pragma unroll
  for (int i = 0; i < 8; ++i) {
    unsigned short h[8];
#pragma unroll
    for (int j = 0; j < 8; ++j) h[j] = f2bf(v[i * 8 + j]);
    *(s8v*)(eo + i * 8) = *(s8v*)h;
  }
  sums[seg][t & 63] = s;
  __syncthreads();
  if (t < 64)
    esq[blockIdx.x * 64 + t] =
        ((sums[0][t] + sums[1][t]) + sums[2][t]) + sums[3][t];
}

// ---------------- xprep: xhi[n][c] bf16 (transposed) + ||x_n||^2 ------------
// xsq chain is bit-identical to R2-R6 (fp32 fmaf, c ascending, per point).
__global__ __launch_bounds__(256) void xprep_kernel(const float* __restrict__ x,
                                                    unsigned short* __restrict__ xhi,
                                                    float* __restrict__ xsq) {
  __shared__ float xls[DIM][64];   // 64 KB, [c][p]
  const int t = threadIdx.x;
  const int n0 = blockIdx.x * 64;            // grid = NPTS/64 = 512
  const int bb = n0 >> 10, hw0 = n0 & 1023;
  const int p = t & 63, cs = t >> 6;
  const float* xb = x + (size_t)bb * CHW + hw0;
#pragma unroll 8
  for (int r = 0; r < 64; ++r) {
    const int c = r * 4 + cs;
    xls[c][p] = xb[(size_t)c * 1024 + p];
  }
  __syncthreads();
  if (t < 64) {
    float s = 0.f;
#pragma unroll 8
    for (int c = 0; c < 256; ++c) {
      const float v = xls[c][t];
      s = fmaf(v, v, s);
    }
    xsq[n0 + t] = s;
  }
  const int p2 = t >> 2, cb = (t & 3) * 64;
  unsigned short* xo = xhi + (size_t)(n0 + p2) * DIM + cb;
#pragma unroll
  for (int i = 0; i < 8; ++i) {
    unsigned short h[8];
#pragma unroll
    for (int j = 0; j < 8; ++j) h[j] = f2bf(xls[cb + i * 8 + j][p2]);
    *(s8v*)(xo + i * 8) = *(s8v*)h;
  }
}

// ---------------- coarse argmin: bf16 MFMA + candidate emission -------------
// Block: 128n x 128k, 4 waves (2x2), wave tile 64x64 = 4x4 MFMA 16x16x32.
// grid = (NPTS/128, 8 k-splits). Margin M=1e-3 (~18 sigma of bf16-split error)
// guarantees the exact winner is emitted (Bernstein tail ~e-63).
constexpr float MARGIN = 1e-3f;
__global__ __launch_bounds__(256) void coarse_kernel(
    const unsigned short* __restrict__ xhi, const unsigned short* __restrict__ ehi,
    const float* __restrict__ esq, const float* __restrict__ xsq,
    float* __restrict__ part, unsigned int* __restrict__ cand) {
  __shared__ __align__(16) unsigned short xs[128][32];   // 8 KB
  __shared__ __align__(16) unsigned short es[128][32];   // 8 KB
  __shared__ float xsq_s[128], esq_s[128], thr_s[128];
  __shared__ unsigned long long red2[2][128];
  __shared__ unsigned int cntL[128];

  const int t = threadIdx.x;
  const int lane = t & 63, w = t >> 6;
  const int wn = (w & 1) * 64, wk = (w >> 1) * 64;
  const int col = lane & 15, quad = lane >> 4;
  const int nblk = blockIdx.x * 128;
  const int kblk = blockIdx.y * 128;

  if (t < 128) {
    xsq_s[t] = xsq[nblk + t];
    esq_s[t] = esq[kblk + t];
    cntL[t] = 0u;
  }

  f32x4 acc[4][4];
#pragma unroll
  for (int i = 0; i < 4; ++i)
#pragma unroll
    for (int j = 0; j < 4; ++j) acc[i][j] = (f32x4){0.f, 0.f, 0.f, 0.f};

  const int gl_row = lane >> 2;        // row within 16-row staging inst
  const int gl_c   = (lane & 3) * 8;   // bf16 col offset

  for (int c0 = 0; c0 < DIM; c0 += 32) {
    __syncthreads();   // previous tile fully consumed (drains lgkm+vm)
#pragma unroll
    for (int i = 0; i < 2; ++i) {
      const int inst = w + 4 * i;                 // wave-uniform
      const int row = inst * 16 + gl_row;
      GLD_LDS16(xhi + (size_t)(nblk + row) * DIM + c0 + gl_c, &xs[inst * 16][0]);
      GLD_LDS16(ehi + (size_t)(kblk + row) * DIM + c0 + gl_c, &es[inst * 16][0]);
    }
    __syncthreads();   // vmcnt(0): tiles visible
    s8v a[4], b[4];
#pragma unroll
    for (int ti = 0; ti < 4; ++ti)
      a[ti] = *(const s8v*)&xs[wn + ti * 16 + col][quad * 8];
#pragma unroll
    for (int tj = 0; tj < 4; ++tj)
      b[tj] = *(const s8v*)&es[wk + tj * 16 + col][quad * 8];
#pragma unroll
    for (int ti = 0; ti < 4; ++ti)
#pragma unroll
      for (int tj = 0; tj < 4; ++tj)
        acc[ti][tj] = __builtin_amdgcn_mfma_f32_16x16x32_bf16(
            a[ti], b[tj], acc[ti][tj], 0, 0, 0);
  }

  // fold: per-thread per-n packed (d,k) min over its 4 k-tiles
  unsigned long long nmin[4][4];
#pragma unroll
  for (int ti = 0; ti < 4; ++ti)
#pragma unroll
    for (int r = 0; r < 4; ++r) nmin[ti][r] = ~0ULL;
#pragma unroll
  for (int ti = 0; ti < 4; ++ti)
#pragma unroll
    for (int tj = 0; tj < 4; ++tj) {
      const int krel = wk + tj * 16 + col;
      const float eq = esq_s[krel];
#pragma unroll
      for (int r = 0; r < 4; ++r) {
        const int nl = wn + ti * 16 + quad * 4 + r;
        const float d = (xsq_s[nl] + eq) - 2.f * acc[ti][tj][r];
        const unsigned long long key =
            ((unsigned long long)__float_as_uint(d) << 32) |
            (unsigned)(kblk + krel);
        if (key < nmin[ti][r]) nmin[ti][r] = key;   // d>0 -> uint-monotone
      }
    }
  // butterfly over the 16 cols (stays within quad)
#pragma unroll
  for (int o = 1; o < 16; o <<= 1)
#pragma unroll
    for (int ti = 0; ti < 4; ++ti)
#pragma unroll
      for (int r = 0; r < 4; ++r) {
        const unsigned long long v = __shfl_xor(nmin[ti][r], o, 64);
        if (v < nmin[ti][r]) nmin[ti][r] = v;
      }
  if (col == 0) {
#pragma unroll
    for (int ti = 0; ti < 4; ++ti)
#pragma unroll
      for (int r = 0; r < 4; ++r)
        red2[w >> 1][wn + ti * 16 + quad * 4 + r] = nmin[ti][r];
  }
  __syncthreads();
  if (t < 128) {
    const unsigned long long m0 = red2[0][t], m1 = red2[1][t];
    const unsigned long long m = (m1 < m0) ? m1 : m0;
    const float dmin = __uint_as_float((unsigned)(m >> 32));
    part[(size_t)(nblk + t) * 8 + blockIdx.y] = dmin;   // split-min
    thr_s[t] = dmin + MARGIN;
  }
  __syncthreads();
  // emission: all k with coarse d <= split_min + M
#pragma unroll
  for (int ti = 0; ti < 4; ++ti)
#pragma unroll
    for (int tj = 0; tj < 4; ++tj) {
      const int krel = wk + tj * 16 + col;
      const float eq = esq_s[krel];
#pragma unroll
      for (int r = 0; r < 4; ++r) {
        const int nl = wn + ti * 16 + quad * 4 + r;
        const float d = (xsq_s[nl] + eq) - 2.f * acc[ti][tj][r];
        if (d <= thr_s[nl]) {
          const unsigned slot = atomicAdd(&cntL[nl], 1u);
          if (slot < 4u)
            cand[((size_t)(nblk + nl) * 8 + blockIdx.y) * 4 + slot] =
                (unsigned)(kblk + krel);
        }
      }
    }
  __syncthreads();
  if (t < 128) {
    unsigned c = cntL[t];
    const size_t base = ((size_t)(nblk + t) * 8 + blockIdx.y) * 4;
    if (c > 4u) { cand[base + 3] = 0xFFFFFFFEu; c = 3u; }  // overflow -> rescan
    for (unsigned s = c; s < 4u; ++s) cand[base + s] = 0xFFFFFFFFu;
  }
}

// ------- finish: exact resolve + quantized write + loss + one-hot -----------
// Block = 32 points, grid = NPTS/32 = 1024 (~54 KB LDS -> 3 blocks/CU).
// Phase 1 = R6 resolve (bit-identical score chain -> same argmin, which
// passed). Phase 2 = winner-row gather (two 16-pt passes) + coalesced outq +
// loss from the staged xls (same values as global x). Phase 3 = one-hot with
// 16B-aligned float4 stores: enc starts at float offset 1+QELEMS ≡ 1 mod 4,
// so 16B-aligned groups start at k ≡ 3 mod 4: kb = 3+4g, g = 0..254 (255
// groups, k=3..1022); edges k=0,1,2 and k=1023 scalar. Full 1024 coverage.
__global__ __launch_bounds__(256) void finish_kernel(
    const float* __restrict__ x, const float* __restrict__ emb,
    const float* __restrict__ esq, const float* __restrict__ xsq,
    const float* __restrict__ part, const unsigned int* __restrict__ cand,
    float* __restrict__ outq, float* __restrict__ enc,
    float* __restrict__ loss) {
  __shared__ float xls[DIM][32];                 // 32 KB, [c][p]
  __shared__ float tile[DIM][16];                // 16 KB, [c][p16]
  __shared__ unsigned list[1024];                // 4 KB worklist
  __shared__ unsigned long long best[32];
  __shared__ float thr_s[32], xsq_s[32];
  __shared__ int ids[32];
  __shared__ float lred[4];
  __shared__ int lcnt;

  const int t = threadIdx.x;
  const int n0 = blockIdx.x * 32;
  const int bb = n0 >> 10, hw0 = n0 & 1023;

  // ---- stage x tile once (coalesced, 128B segments) ----
  const float* xb = x + (size_t)bb * CHW + hw0;
  {
    const int p = t & 31, cs = t >> 5;
#pragma unroll 8
    for (int r = 0; r < 32; ++r) {
      const int c = r * 8 + cs;
      xls[c][p] = xb[(size_t)c * 1024 + p];
    }
  }
  if (t == 0) lcnt = 0;
  if (t < 32) {
    best[t] = ~0ULL;
    xsq_s[t] = xsq[n0 + t];
    const float4 p0 = *(const float4*)&part[(size_t)(n0 + t) * 8];
    const float4 p1 = *(const float4*)&part[(size_t)(n0 + t) * 8 + 4];
    float g = fminf(fminf(fminf(p0.x, p0.y), fminf(p0.z, p0.w)),
                    fminf(fminf(p1.x, p1.y), fminf(p1.z, p1.w)));
    thr_s[t] = g + MARGIN;
  }
  __syncthreads();

  // ---- build worklist: thread t -> (point nn = t>>3, split s = t&7) ----
  {
    const int nn = t >> 3, s = t & 7;
    const float pv = part[(size_t)(n0 + nn) * 8 + s];
    if (pv <= thr_s[nn]) {
      const uint4 c4 = *(const uint4*)&cand[((size_t)(n0 + nn) * 8 + s) * 4];
      const unsigned vs[4] = {c4.x, c4.y, c4.z, c4.w};
#pragma unroll
      for (int i = 0; i < 4; ++i) {
        const unsigned v = vs[i];
        if (v == 0xFFFFFFFFu) continue;
        const unsigned entry = (v == 0xFFFFFFFEu)
                                   ? ((unsigned)nn << 11) | 1024u | (unsigned)s
                                   : ((unsigned)nn << 11) | (v & 1023u);
        const int pos = atomicAdd(&lcnt, 1);
        if (pos < 1024) list[pos] = entry;   // bound: 32*8*4 = 1024
      }
    }
  }
  __syncthreads();

  // ---- consume worklist; score chain bit-identical to R5/R6 ----
  const int L = lcnt < 1024 ? lcnt : 1024;
  for (int e = t; e < L; e += 256) {
    const unsigned entry = list[e];
    const int p = entry >> 11;
    const float xq = xsq_s[p];
    int klo, khi;
    if (entry & 1024u) { const int s = entry & 7; klo = s * 128; khi = klo + 128; }
    else               { klo = entry & 1023u; khi = klo + 1; }
    for (int k = klo; k < khi; ++k) {
      const float* er = emb + (size_t)k * DIM;
      float dot = 0.f;
#pragma unroll 4
      for (int c4 = 0; c4 < DIM; c4 += 4) {
        const float4 e4 = *(const float4*)(er + c4);
        dot = fmaf(xls[c4 + 0][p], e4.x, dot);
        dot = fmaf(xls[c4 + 1][p], e4.y, dot);
        dot = fmaf(xls[c4 + 2][p], e4.z, dot);
        dot = fmaf(xls[c4 + 3][p], e4.w, dot);
      }
      const float t1 = xq + esq[k];
      const float d = t1 - 2.f * dot;
      const unsigned long long key =
          ((unsigned long long)__float_as_uint(d) << 32) | (unsigned)k;
      atomicMin(&best[p], key);   // d>0 -> uint-monotone; low k wins ties
    }
  }
  __syncthreads();
  if (t < 32) ids[t] = (int)(best[t] & 0xFFFFFFFFu);
  __syncthreads();

  // ---- quantized write + loss, two 16-point passes ----
  float lsum = 0.f;
  float* ob = outq + (size_t)bb * CHW + hw0;
#pragma unroll
  for (int h = 0; h < 2; ++h) {
    const int p16 = t & 15, cs16 = t >> 4;   // 16 segs x 16 c
    const int row = ids[h * 16 + p16];
    const float* er = emb + (size_t)row * DIM + cs16 * 16;
#pragma unroll
    for (int i = 0; i < 4; ++i) {
      const float4 v = *(const float4*)(er + i * 4);
      const int c = cs16 * 16 + i * 4;
      tile[c + 0][p16] = v.x;
      tile[c + 1][p16] = v.y;
      tile[c + 2][p16] = v.z;
      tile[c + 3][p16] = v.w;
    }
    __syncthreads();
#pragma unroll
    for (int i = 0; i < 16; ++i) {
      const int c = cs16 + i * 16;
      const float q  = tile[c][p16];
      const float xv = xls[c][h * 16 + p16];
      ob[(size_t)c * 1024 + h * 16 + p16] = q;   // 64B segments, scalar
      const float d = q - xv;
      lsum = fmaf(d, d, lsum);
    }
    __syncthreads();   // tile reuse in next pass
  }
  float s = lsum;
#pragma unroll
  for (int o = 32; o > 0; o >>= 1) s += __shfl_down(s, o, 64);
  if ((t & 63) == 0) lred[t >> 6] = s;

  // ---- one-hot encodings: 255 float4 groups (k=3..1022) + edge floats ----
  if (t < 255) {
    const int kb = 3 + 4 * t;
#pragma unroll 4
    for (int r = 0; r < 32; ++r) {
      const int id = ids[r];
      float4 v = {0.f, 0.f, 0.f, 0.f};
      const unsigned rel = (unsigned)(id - kb);
      if (rel < 4u) ((float*)&v)[rel] = 1.f;
      *(float4*)(enc + (size_t)(n0 + r) * K + kb) = v;
    }
  } else {
    for (int r = 0; r < 32; ++r) {
      const int id = ids[r];
      float* eb = enc + (size_t)(n0 + r) * K;
      eb[0] = (id == 0) ? 1.f : 0.f;
      eb[1] = (id == 1) ? 1.f : 0.f;
      eb[2] = (id == 2) ? 1.f : 0.f;
      eb[1023] = (id == 1023) ? 1.f : 0.f;
    }
  }

  __syncthreads();
  if (t == 0) {
    const float tot = (lred[0] + lred[1] + lred[2] + lred[3]) * (1.25f / (float)QELEMS);
    atomicAdd(loss, tot);   // loss = q_latent + 0.25*e_latent = 1.25 * MSE
  }
}

extern "C" void kernel_launch(void* const* d_in, const int* in_sizes, int n_in,
                              void* d_out, int out_size, void* d_ws, size_t ws_size,
                              hipStream_t stream) {
  const float* x   = (const float*)d_in[0];
  const float* emb = (const float*)d_in[1];
  float* out  = (float*)d_out;
  float* loss = out;                       // [1]
  float* outq = out + 1;                   // [8388608], 4B-aligned only
  float* enc  = out + 1 + QELEMS;          // [33554432], 4B-aligned only

  char* ws = (char*)d_ws;
  unsigned short* ehi  = (unsigned short*)ws;                  // 512 KB
  float*          esq  = (float*)(ws + 524288);                // 4 KB
  float*          xsq  = (float*)(ws + 528384);                // 128 KB
  float*          part = (float*)(ws + 659456);                // 1 MB
  unsigned int*   cand = (unsigned int*)(ws + 1708032);        // 4 MB
  unsigned short* xhi  = (unsigned short*)(ws + 5902336);      // 16 MB
  // total ws use: ~22.7 MB

  hipMemsetAsync(loss, 0, sizeof(float), stream);

  eprep_kernel<<<K / 64, 256, 0, stream>>>(emb, ehi, esq);
  xprep_kernel<<<NPTS / 64, 256, 0, stream>>>(x, xhi, xsq);
  dim3 cg(NPTS / 128, 8);
  coarse_kernel<<<cg, 256, 0, stream>>>(xhi, ehi, esq, xsq, part, cand);
  finish_kernel<<<NPTS / 32, 256, 0, stream>>>(x, emb, esq, xsq, part, cand,
                                               outq, enc, loss);
}

// Round 9
// 294.394 us; speedup vs baseline: 1.0574x; 1.0574x over previous
//
#include <hip/hip_runtime.h>
#include <cstdint>
#include <cstddef>

// Problem constants
constexpr int B = 32, C = 256, H = 32, W = 32;
constexpr int NPTS = B * H * W;          // 32768 points
constexpr int DIM  = 256;                // embedding dim
constexpr int K    = 1024;               // codebook size
constexpr int QELEMS = B * C * H * W;    // 8388608 quantized elements
constexpr int CHW = C * H * W;           // 262144

typedef __attribute__((ext_vector_type(8))) short s8v;    // 8 bf16 (4 VGPRs)
typedef __attribute__((ext_vector_type(4))) float f32x4;  // MFMA acc

// Async global->LDS, 16B per lane. LDS dest is wave-uniform base + lane*16.
#define GLD_LDS16(g, l)                                                        \
  __builtin_amdgcn_global_load_lds(                                            \
      (const __attribute__((address_space(1))) unsigned int*)(g),              \
      (__attribute__((address_space(3))) unsigned int*)(l), 16, 0, 0)

__device__ __forceinline__ unsigned short f2bf(float f) {  // RNE fp32->bf16
  unsigned u = __float_as_uint(f);
  return (unsigned short)((u + 0x7FFFu + ((u >> 16) & 1u)) >> 16);
}

// ---------------- prep: eprep (blocks 0..15) + xprep (blocks 16..527) -------
// eprep: ehi[k][c] bf16 + ||e_k||^2 (chain identical to R8's eprep).
// xprep: xhi[n][c] bf16 + ||x_n||^2 (chain identical to R2-R8: fp32 fmaf,
// c ascending, per point). Block 0 thread 0 also zeros loss (runs before
// finish in stream order). LDS: one 64 KB array, eprep aliases its head.
__global__ __launch_bounds__(256) void prep_kernel(
    const float* __restrict__ x, const float* __restrict__ emb,
    unsigned short* __restrict__ ehi, float* __restrict__ esq,
    unsigned short* __restrict__ xhi, float* __restrict__ xsq,
    float* __restrict__ loss) {
  __shared__ float xls[DIM][64];   // 64 KB; eprep uses first 1 KB as sums[4][64]
  const int t = threadIdx.x;

  if (blockIdx.x < 16) {
    if (blockIdx.x == 0 && t == 0) *loss = 0.f;
    float (*sums)[64] = (float (*)[64])xls;
    const int k = blockIdx.x * 64 + (t & 63);
    const int seg = t >> 6;                     // 4 segs x 64 c
    const float* er = emb + (size_t)k * DIM + seg * 64;
    float v[64];
    float4* v4 = (float4*)v;
#pragma unroll
    for (int i = 0; i < 16; ++i) v4[i] = *(const float4*)(er + i * 4);
    float s = 0.f;
#pragma unroll
    for (int i = 0; i < 64; ++i) s = fmaf(v[i], v[i], s);
    unsigned short* eo = ehi + (size_t)k * DIM + seg * 64;
#pragma unroll
    for (int i = 0; i < 8; ++i) {
      unsigned short h[8];
#pragma unroll
      for (int j = 0; j < 8; ++j) h[j] = f2bf(v[i * 8 + j]);
      *(s8v*)(eo + i * 8) = *(s8v*)h;
    }
    sums[seg][t & 63] = s;
    __syncthreads();
    if (t < 64)
      esq[blockIdx.x * 64 + t] =
          ((sums[0][t] + sums[1][t]) + sums[2][t]) + sums[3][t];
    return;
  }

  const int n0 = (blockIdx.x - 16) * 64;        // 512 x-blocks
  const int bb = n0 >> 10, hw0 = n0 & 1023;
  const int p = t & 63, cs = t >> 6;
  const float* xb = x + (size_t)bb * CHW + hw0;
#pragma unroll 8
  for (int r = 0; r < 64; ++r) {
    const int c = r * 4 + cs;
    xls[c][p] = xb[(size_t)c * 1024 + p];
  }
  __syncthreads();
  if (t < 64) {
    float s = 0.f;
#pragma unroll 8
    for (int c = 0; c < 256; ++c) {
      const float v = xls[c][t];
      s = fmaf(v, v, s);
    }
    xsq[n0 + t] = s;
  }
  const int p2 = t >> 2, cb = (t & 3) * 64;
  unsigned short* xo = xhi + (size_t)(n0 + p2) * DIM + cb;
#pragma unroll
  for (int i = 0; i < 8; ++i) {
    unsigned short h[8];
#pragma unroll
    for (int j = 0; j < 8; ++j) h[j] = f2bf(xls[cb + i * 8 + j][p2]);
    *(s8v*)(xo + i * 8) = *(s8v*)h;
  }
}

// ---------------- coarse argmin: bf16 MFMA + candidate emission -------------
// Block: 128n x 128k, 4 waves (2x2), wave tile 64x64 = 4x4 MFMA 16x16x32.
// grid = (NPTS/128, 8 k-splits). Margin M=1e-3 (~18 sigma of bf16-split error)
// guarantees the exact winner is emitted (Bernstein tail ~e-63).
constexpr float MARGIN = 1e-3f;
__global__ __launch_bounds__(256) void coarse_kernel(
    const unsigned short* __restrict__ xhi, const unsigned short* __restrict__ ehi,
    const float* __restrict__ esq, const float* __restrict__ xsq,
    float* __restrict__ part, unsigned int* __restrict__ cand) {
  __shared__ __align__(16) unsigned short xs[128][32];   // 8 KB
  __shared__ __align__(16) unsigned short es[128][32];   // 8 KB
  __shared__ float xsq_s[128], esq_s[128], thr_s[128];
  __shared__ unsigned long long red2[2][128];
  __shared__ unsigned int cntL[128];

  const int t = threadIdx.x;
  const int lane = t & 63, w = t >> 6;
  const int wn = (w & 1) * 64, wk = (w >> 1) * 64;
  const int col = lane & 15, quad = lane >> 4;
  const int nblk = blockIdx.x * 128;
  const int kblk = blockIdx.y * 128;

  if (t < 128) {
    xsq_s[t] = xsq[nblk + t];
    esq_s[t] = esq[kblk + t];
    cntL[t] = 0u;
  }

  f32x4 acc[4][4];
#pragma unroll
  for (int i = 0; i < 4; ++i)
#pragma unroll
    for (int j = 0; j < 4; ++j) acc[i][j] = (f32x4){0.f, 0.f, 0.f, 0.f};

  const int gl_row = lane >> 2;        // row within 16-row staging inst
  const int gl_c   = (lane & 3) * 8;   // bf16 col offset

  for (int c0 = 0; c0 < DIM; c0 += 32) {
    __syncthreads();   // previous tile fully consumed (drains lgkm+vm)
#pragma unroll
    for (int i = 0; i < 2; ++i) {
      const int inst = w + 4 * i;                 // wave-uniform
      const int row = inst * 16 + gl_row;
      GLD_LDS16(xhi + (size_t)(nblk + row) * DIM + c0 + gl_c, &xs[inst * 16][0]);
      GLD_LDS16(ehi + (size_t)(kblk + row) * DIM + c0 + gl_c, &es[inst * 16][0]);
    }
    __syncthreads();   // vmcnt(0): tiles visible
    s8v a[4], b[4];
#pragma unroll
    for (int ti = 0; ti < 4; ++ti)
      a[ti] = *(const s8v*)&xs[wn + ti * 16 + col][quad * 8];
#pragma unroll
    for (int tj = 0; tj < 4; ++tj)
      b[tj] = *(const s8v*)&es[wk + tj * 16 + col][quad * 8];
#pragma unroll
    for (int ti = 0; ti < 4; ++ti)
#pragma unroll
      for (int tj = 0; tj < 4; ++tj)
        acc[ti][tj] = __builtin_amdgcn_mfma_f32_16x16x32_bf16(
            a[ti], b[tj], acc[ti][tj], 0, 0, 0);
  }

  // fold: per-thread per-n packed (d,k) min over its 4 k-tiles
  unsigned long long nmin[4][4];
#pragma unroll
  for (int ti = 0; ti < 4; ++ti)
#pragma unroll
    for (int r = 0; r < 4; ++r) nmin[ti][r] = ~0ULL;
#pragma unroll
  for (int ti = 0; ti < 4; ++ti)
#pragma unroll
    for (int tj = 0; tj < 4; ++tj) {
      const int krel = wk + tj * 16 + col;
      const float eq = esq_s[krel];
#pragma unroll
      for (int r = 0; r < 4; ++r) {
        const int nl = wn + ti * 16 + quad * 4 + r;
        const float d = (xsq_s[nl] + eq) - 2.f * acc[ti][tj][r];
        const unsigned long long key =
            ((unsigned long long)__float_as_uint(d) << 32) |
            (unsigned)(kblk + krel);
        if (key < nmin[ti][r]) nmin[ti][r] = key;   // d>0 -> uint-monotone
      }
    }
  // butterfly over the 16 cols (stays within quad)
#pragma unroll
  for (int o = 1; o < 16; o <<= 1)
#pragma unroll
    for (int ti = 0; ti < 4; ++ti)
#pragma unroll
      for (int r = 0; r < 4; ++r) {
        const unsigned long long v = __shfl_xor(nmin[ti][r], o, 64);
        if (v < nmin[ti][r]) nmin[ti][r] = v;
      }
  if (col == 0) {
#pragma unroll
    for (int ti = 0; ti < 4; ++ti)
#pragma unroll
      for (int r = 0; r < 4; ++r)
        red2[w >> 1][wn + ti * 16 + quad * 4 + r] = nmin[ti][r];
  }
  __syncthreads();
  if (t < 128) {
    const unsigned long long m0 = red2[0][t], m1 = red2[1][t];
    const unsigned long long m = (m1 < m0) ? m1 : m0;
    const float dmin = __uint_as_float((unsigned)(m >> 32));
    part[(size_t)(nblk + t) * 8 + blockIdx.y] = dmin;   // split-min
    thr_s[t] = dmin + MARGIN;
  }
  __syncthreads();
  // emission: all k with coarse d <= split_min + M
#pragma unroll
  for (int ti = 0; ti < 4; ++ti)
#pragma unroll
    for (int tj = 0; tj < 4; ++tj) {
      const int krel = wk + tj * 16 + col;
      const float eq = esq_s[krel];
#pragma unroll
      for (int r = 0; r < 4; ++r) {
        const int nl = wn + ti * 16 + quad * 4 + r;
        const float d = (xsq_s[nl] + eq) - 2.f * acc[ti][tj][r];
        if (d <= thr_s[nl]) {
          const unsigned slot = atomicAdd(&cntL[nl], 1u);
          if (slot < 4u)
            cand[((size_t)(nblk + nl) * 8 + blockIdx.y) * 4 + slot] =
                (unsigned)(kblk + krel);
        }
      }
    }
  __syncthreads();
  if (t < 128) {
    unsigned c = cntL[t];
    const size_t base = ((size_t)(nblk + t) * 8 + blockIdx.y) * 4;
    if (c > 4u) { cand[base + 3] = 0xFFFFFFFEu; c = 3u; }  // overflow -> rescan
    for (unsigned s = c; s < 4u; ++s) cand[base + s] = 0xFFFFFFFFu;
  }
}

// ------- finish: exact resolve + quantized write + loss + one-hot -----------
// Block = 32 points, grid = NPTS/32 = 1024. LDS = xls(32K) + 16.6 KB union:
// phase 1 {list, best, thr, xsq, lcnt} aliased under phase 2 {tile, ids, lred}
// -> 48.3 KB total -> 3 blocks/CU (R8 was 53.9 KB -> 2/CU, the regression).
// Phase 1 score chain bit-identical to R5-R8 (passed) -> same argmin.
__global__ __launch_bounds__(256) void finish_kernel(
    const float* __restrict__ x, const float* __restrict__ emb,
    const float* __restrict__ esq, const float* __restrict__ xsq,
    const float* __restrict__ part, const unsigned int* __restrict__ cand,
    float* __restrict__ outq, float* __restrict__ enc,
    float* __restrict__ loss) {
  __shared__ __align__(16) float xls[DIM][32];   // 32 KB, [c][p], live whole kernel
  __shared__ __align__(16) char smem2[16640];    // phase-overlaid region
  // phase 1 (worklist/resolve):
  unsigned* list            = (unsigned*)smem2;                    // 4096 B
  unsigned long long* best  = (unsigned long long*)(smem2 + 4096); // 256 B
  float* thr_s              = (float*)(smem2 + 4352);              // 128 B
  float* xsq_s              = (float*)(smem2 + 4480);              // 128 B
  int* lcnt                 = (int*)(smem2 + 4608);                // 4 B
  // phase 2 (gather/write) — overlays phase 1 after ids extraction:
  float (*tile)[16]         = (float (*)[16])smem2;                // 16384 B
  int* ids                  = (int*)(smem2 + 16384);               // 128 B
  float* lred               = (float*)(smem2 + 16512);             // 16 B

  const int t = threadIdx.x;
  const int n0 = blockIdx.x * 32;
  const int bb = n0 >> 10, hw0 = n0 & 1023;

  // ---- stage x tile once (coalesced, 128B segments) ----
  const float* xb = x + (size_t)bb * CHW + hw0;
  {
    const int p = t & 31, cs = t >> 5;
#pragma unroll 8
    for (int r = 0; r < 32; ++r) {
      const int c = r * 8 + cs;
      xls[c][p] = xb[(size_t)c * 1024 + p];
    }
  }
  if (t == 0) *lcnt = 0;
  if (t < 32) {
    best[t] = ~0ULL;
    xsq_s[t] = xsq[n0 + t];
    const float4 p0 = *(const float4*)&part[(size_t)(n0 + t) * 8];
    const float4 p1 = *(const float4*)&part[(size_t)(n0 + t) * 8 + 4];
    float g = fminf(fminf(fminf(p0.x, p0.y), fminf(p0.z, p0.w)),
                    fminf(fminf(p1.x, p1.y), fminf(p1.z, p1.w)));
    thr_s[t] = g + MARGIN;
  }
  __syncthreads();

  // ---- build worklist: thread t -> (point nn = t>>3, split s = t&7) ----
  {
    const int nn = t >> 3, s = t & 7;
    const float pv = part[(size_t)(n0 + nn) * 8 + s];
    if (pv <= thr_s[nn]) {
      const uint4 c4 = *(const uint4*)&cand[((size_t)(n0 + nn) * 8 + s) * 4];
      const unsigned vs[4] = {c4.x, c4.y, c4.z, c4.w};
#pragma unroll
      for (int i = 0; i < 4; ++i) {
        const unsigned v = vs[i];
        if (v == 0xFFFFFFFFu) continue;
        const unsigned entry = (v == 0xFFFFFFFEu)
                                   ? ((unsigned)nn << 11) | 1024u | (unsigned)s
                                   : ((unsigned)nn << 11) | (v & 1023u);
        const int pos = atomicAdd(lcnt, 1);
        if (pos < 1024) list[pos] = entry;   // bound: 32*8*4 = 1024
      }
    }
  }
  __syncthreads();

  // ---- consume worklist; score chain bit-identical to R5-R8 ----
  const int L = *lcnt < 1024 ? *lcnt : 1024;
  for (int e = t; e < L; e += 256) {
    const unsigned entry = list[e];
    const int p = entry >> 11;
    const float xq = xsq_s[p];
    int klo, khi;
    if (entry & 1024u) { const int s = entry & 7; klo = s * 128; khi = klo + 128; }
    else               { klo = entry & 1023u; khi = klo + 1; }
    for (int k = klo; k < khi; ++k) {
      const float* er = emb + (size_t)k * DIM;
      float dot = 0.f;
#pragma unroll 4
      for (int c4 = 0; c4 < DIM; c4 += 4) {
        const float4 e4 = *(const float4*)(er + c4);
        dot = fmaf(xls[c4 + 0][p], e4.x, dot);
        dot = fmaf(xls[c4 + 1][p], e4.y, dot);
        dot = fmaf(xls[c4 + 2][p], e4.z, dot);
        dot = fmaf(xls[c4 + 3][p], e4.w, dot);
      }
      const float t1 = xq + esq[k];
      const float d = t1 - 2.f * dot;
      const unsigned long long key =
          ((unsigned long long)__float_as_uint(d) << 32) | (unsigned)k;
      atomicMin(&best[p], key);   // d>0 -> uint-monotone; low k wins ties
    }
  }
  __syncthreads();
  if (t < 32) ids[t] = (int)(best[t] & 0xFFFFFFFFu);   // ids @16384, best @4096
  __syncthreads();   // phase 1 region now dead; tile may overwrite it

  // ---- quantized write + loss, two 16-point passes ----
  float lsum = 0.f;
  float* ob = outq + (size_t)bb * CHW + hw0;
#pragma unroll
  for (int h = 0; h < 2; ++h) {
    const int p16 = t & 15, cs16 = t >> 4;   // 16 segs x 16 c
    const int row = ids[h * 16 + p16];
    const float* er = emb + (size_t)row * DIM + cs16 * 16;
#pragma unroll
    for (int i = 0; i < 4; ++i) {
      const float4 v = *(const float4*)(er + i * 4);
      const int c = cs16 * 16 + i * 4;
      tile[c + 0][p16] = v.x;
      tile[c + 1][p16] = v.y;
      tile[c + 2][p16] = v.z;
      tile[c + 3][p16] = v.w;
    }
    __syncthreads();
#pragma unroll
    for (int i = 0; i < 16; ++i) {
      const int c = cs16 + i * 16;
      const float q  = tile[c][p16];
      const float xv = xls[c][h * 16 + p16];
      ob[(size_t)c * 1024 + h * 16 + p16] = q;   // 64B segments, scalar
      const float d = q - xv;
      lsum = fmaf(d, d, lsum);
    }
    __syncthreads();   // tile reuse in next pass
  }
  float s = lsum;
#pragma unroll
  for (int o = 32; o > 0; o >>= 1) s += __shfl_down(s, o, 64);
  if ((t & 63) == 0) lred[t >> 6] = s;

  // ---- one-hot encodings: 255 float4 groups (k=3..1022) + edge floats ----
  // enc starts at float offset 1+QELEMS ≡ 1 mod 4 -> 16B-aligned groups at
  // k ≡ 3 mod 4. Full coverage: 255*4 + {0,1,2,1023} = 1024.
  if (t < 255) {
    const int kb = 3 + 4 * t;
#pragma unroll 4
    for (int r = 0; r < 32; ++r) {
      const int id = ids[r];
      float4 v = {0.f, 0.f, 0.f, 0.f};
      const unsigned rel = (unsigned)(id - kb);
      if (rel < 4u) ((float*)&v)[rel] = 1.f;
      *(float4*)(enc + (size_t)(n0 + r) * K + kb) = v;
    }
  } else {
    for (int r = 0; r < 32; ++r) {
      const int id = ids[r];
      float* eb = enc + (size_t)(n0 + r) * K;
      eb[0] = (id == 0) ? 1.f : 0.f;
      eb[1] = (id == 1) ? 1.f : 0.f;
      eb[2] = (id == 2) ? 1.f : 0.f;
      eb[1023] = (id == 1023) ? 1.f : 0.f;
    }
  }

  __syncthreads();
  if (t == 0) {
    const float tot = (lred[0] + lred[1] + lred[2] + lred[3]) * (1.25f / (float)QELEMS);
    atomicAdd(loss, tot);   // loss = q_latent + 0.25*e_latent = 1.25 * MSE
  }
}

extern "C" void kernel_launch(void* const* d_in, const int* in_sizes, int n_in,
                              void* d_out, int out_size, void* d_ws, size_t ws_size,
                              hipStream_t stream) {
  const float* x   = (const float*)d_in[0];
  const float* emb = (const float*)d_in[1];
  float* out  = (float*)d_out;
  float* loss = out;                       // [1]
  float* outq = out + 1;                   // [8388608], 4B-aligned only
  float* enc  = out + 1 + QELEMS;          // [33554432], 4B-aligned only

  char* ws = (char*)d_ws;
  unsigned short* ehi  = (unsigned short*)ws;                  // 512 KB
  float*          esq  = (float*)(ws + 524288);                // 4 KB
  float*          xsq  = (float*)(ws + 528384);                // 128 KB
  float*          part = (float*)(ws + 659456);                // 1 MB
  unsigned int*   cand = (unsigned int*)(ws + 1708032);        // 4 MB
  unsigned short* xhi  = (unsigned short*)(ws + 5902336);      // 16 MB
  // total ws use: ~22.7 MB

  prep_kernel<<<16 + NPTS / 64, 256, 0, stream>>>(x, emb, ehi, esq, xhi, xsq,
                                                  loss);
  dim3 cg(NPTS / 128, 8);
  coarse_kernel<<<cg, 256, 0, stream>>>(xhi, ehi, esq, xsq, part, cand);
  finish_kernel<<<NPTS / 32, 256, 0, stream>>>(x, emb, esq, xsq, part, cand,
                                               outq, enc, loss);
}